// Round 1
// baseline (408.288 us; speedup 1.0000x reference)
//
#include <hip/hip_runtime.h>
#include <cstddef>

namespace {

constexpr int Bn   = 8;
constexpr int Cc   = 128;
constexpr int Hh   = 56;
constexpr int Ww   = 56;
constexpr int OUTC = 128;
constexpr int NTAP = 9;            // K*K
constexpr int HW   = Hh * Ww;      // 3136
constexpr int NPOS = Bn * HW;      // 25088
constexpr int KDIM = Cc * NTAP;    // 1152

constexpr int PT  = 32;            // positions per block (3136 % 32 == 0 -> never straddles batch)
constexpr int CCH = 16;            // channel chunk

// padded-map read: xp[qy][qx] on 58x58, xc points at x[b][c] (56x56)
__device__ __forceinline__ float ldpad(const float* __restrict__ xc, int yy, int xx) {
    return ((unsigned)yy < (unsigned)Hh && (unsigned)xx < (unsigned)Ww) ? xc[yy * Ww + xx] : 0.f;
}

// ---------------------------------------------------------------------------
// Kernel 1: offset conv (3x3, pad 1) + bias, then p = p0 + pn + offset.
// One thread per (b, m, i, j); blockIdx.y = b*18+m.
// ---------------------------------------------------------------------------
__global__ __launch_bounds__(256) void offset_p_kernel(
        const float* __restrict__ x, const float* __restrict__ ow,
        const float* __restrict__ ob, float* __restrict__ pbuf) {
    const int bm = blockIdx.y;
    const int m = bm % 18, b = bm / 18;
    const int pos = blockIdx.x * 256 + threadIdx.x;
    if (pos >= HW) return;
    const int i = pos / Ww, j = pos % Ww;

    const float* xb = x + (size_t)b * Cc * HW;
    const float* wb = ow + (size_t)m * Cc * NTAP;

    float acc = 0.f;
    for (int c = 0; c < Cc; ++c) {
        const float* xc = xb + (size_t)c * HW;
        const float* wc = wb + c * NTAP;
#pragma unroll
        for (int ky = 0; ky < 3; ++ky) {
            const int y = i + ky - 1;
            const bool yv = (unsigned)y < (unsigned)Hh;
#pragma unroll
            for (int kx = 0; kx < 3; ++kx) {
                const int xx = j + kx - 1;
                const float v = (yv && (unsigned)xx < (unsigned)Ww) ? xc[y * Ww + xx] : 0.f;
                acc = fmaf(wc[ky * 3 + kx], v, acc);
            }
        }
    }
    acc += ob[m];  // offset = conv + bias

    // p0 + pn (exact small integers), y-first channels then x
    float base;
    if (m < 9)  base = (float)(i + 1 + (m / 3) - 1);        // gy[i] + pn_y[n]
    else        base = (float)(j + 1 + ((m - 9) % 3) - 1);  // gx[j] + pn_x[n]
    pbuf[(size_t)bm * HW + pos] = base + acc;
}

// ---------------------------------------------------------------------------
// Kernel 2: fused bilinear(-with-trunc-bug) sampling + GEMM.
// Block: 32 positions x 128 outputs, 256 threads, 4pos x 4o per thread.
// ---------------------------------------------------------------------------
__global__ __launch_bounds__(256) void deform_gemm_kernel(
        const float* __restrict__ x, const float* __restrict__ cw,
        const float* __restrict__ pbuf, float* __restrict__ out) {
    __shared__ float xoffT[CCH * NTAP][PT];   // [144][32] transposed for b128 reads
    __shared__ float gwS[4][PT * NTAP];       // bilinear weights, SoA (conflict-free)
    __shared__ int   qiS[4][PT * NTAP];       // lty, ltx, rby, rbx

    const int t = threadIdx.x;
    const int p0g = blockIdx.x * PT;
    const int b = p0g / HW;
    const int ijbase = p0g % HW;

    // ---- per-(pos, tap) sampling parameters: exact reference arithmetic ----
    for (int e = t; e < PT * NTAP; e += 256) {
        const int lp = e / NTAP, n = e % NTAP;
        const int ij = ijbase + lp;
        const float py = pbuf[(size_t)(b * 18 + n) * HW + ij];
        const float px = pbuf[(size_t)(b * 18 + 9 + n) * HW + ij];
        const float q0y = floorf(py), q0x = floorf(px);
        const float lty = fminf(fmaxf(q0y, 0.f), 57.f);
        const float ltx = fminf(fmaxf(q0x, 0.f), 57.f);
        const float rby = fminf(fmaxf(q0y + 1.f, 0.f), 57.f);
        const float rbx = fminf(fmaxf(q0x + 1.f, 0.f), 57.f);
        const float pyc = fminf(fmaxf(py, 0.f), 57.f);
        const float pxc = fminf(fmaxf(px, 0.f), 57.f);
        gwS[0][e] = (1.f - (pyc - lty)) * truncf(1.f - (pxc - ltx));  // g_lt
        gwS[1][e] = (1.f - (rby - pyc)) * truncf(1.f - (rbx - pxc));  // g_rb
        gwS[2][e] = (1.f - (pyc - lty)) * (1.f - (rbx - pxc));        // g_lb (lty,rbx)
        gwS[3][e] = (1.f - (rby - pyc)) * (1.f - (pxc - ltx));        // g_rt (rby,ltx)
        qiS[0][e] = (int)lty; qiS[1][e] = (int)ltx;
        qiS[2][e] = (int)rby; qiS[3][e] = (int)rbx;
    }
    __syncthreads();

    float acc[4][4] = {};                 // [pos_sub][o_sub]
    const int po = t & 7;                 // pos quad: pos = po*4+q
    const int og = t >> 3;                // o quad:   o   = og*4+oi
    const int lp = t & 31, cl = t >> 5;   // staging mapping
    const float* xb = x + (size_t)b * Cc * HW;

    for (int c0 = 0; c0 < Cc; c0 += CCH) {
        // ---- stage xoff[k=(ci,n)][pos] into LDS ----
#pragma unroll
        for (int n = 0; n < NTAP; ++n) {
            const int e = lp * NTAP + n;
            const int a0y = qiS[0][e], a0x = qiS[1][e];
            const int a1y = qiS[2][e], a1x = qiS[3][e];
            const float g0 = gwS[0][e], g1 = gwS[1][e];
            const float g2 = gwS[2][e], g3 = gwS[3][e];
            // hoisted gather offsets (padded map -> raw map)
            const int y0 = a0y - 1, y1 = a1y - 1, x0 = a0x - 1, x1 = a1x - 1;
#pragma unroll
            for (int cio = 0; cio < 2; ++cio) {
                const int ci = cl + cio * 8;
                const float* xc = xb + (size_t)(c0 + ci) * HW;
                float v;
                v = g0 * ldpad(xc, y0, x0);
                v = fmaf(g1, ldpad(xc, y1, x1), v);
                v = fmaf(g2, ldpad(xc, y0, x1), v);
                v = fmaf(g3, ldpad(xc, y1, x0), v);
                xoffT[ci * NTAP + n][lp] = v;
            }
        }
        __syncthreads();

        // ---- register-blocked GEMM over this K-chunk ----
        const float* wbase = cw + (size_t)(og * 4) * KDIM + c0 * NTAP;
        for (int ci = 0; ci < CCH; ++ci) {
            const float* wp = wbase + ci * NTAP;
#pragma unroll
            for (int n = 0; n < NTAP; ++n) {
                const float wv0 = wp[n];
                const float wv1 = wp[KDIM + n];
                const float wv2 = wp[2 * KDIM + n];
                const float wv3 = wp[3 * KDIM + n];
                const float4 xv = *(const float4*)&xoffT[ci * NTAP + n][po * 4];
                acc[0][0] = fmaf(wv0, xv.x, acc[0][0]);
                acc[0][1] = fmaf(wv1, xv.x, acc[0][1]);
                acc[0][2] = fmaf(wv2, xv.x, acc[0][2]);
                acc[0][3] = fmaf(wv3, xv.x, acc[0][3]);
                acc[1][0] = fmaf(wv0, xv.y, acc[1][0]);
                acc[1][1] = fmaf(wv1, xv.y, acc[1][1]);
                acc[1][2] = fmaf(wv2, xv.y, acc[1][2]);
                acc[1][3] = fmaf(wv3, xv.y, acc[1][3]);
                acc[2][0] = fmaf(wv0, xv.z, acc[2][0]);
                acc[2][1] = fmaf(wv1, xv.z, acc[2][1]);
                acc[2][2] = fmaf(wv2, xv.z, acc[2][2]);
                acc[2][3] = fmaf(wv3, xv.z, acc[2][3]);
                acc[3][0] = fmaf(wv0, xv.w, acc[3][0]);
                acc[3][1] = fmaf(wv1, xv.w, acc[3][1]);
                acc[3][2] = fmaf(wv2, xv.w, acc[3][2]);
                acc[3][3] = fmaf(wv3, xv.w, acc[3][3]);
            }
        }
        __syncthreads();
    }

    // ---- epilogue ----
    float* outb = out + (size_t)b * OUTC * HW;
#pragma unroll
    for (int q = 0; q < 4; ++q) {
        const int ij = ijbase + po * 4 + q;
#pragma unroll
        for (int oi = 0; oi < 4; ++oi) {
            outb[(size_t)(og * 4 + oi) * HW + ij] = acc[q][oi];
        }
    }
}

}  // namespace

extern "C" void kernel_launch(void* const* d_in, const int* in_sizes, int n_in,
                              void* d_out, int out_size, void* d_ws, size_t ws_size,
                              hipStream_t stream) {
    const float* x  = (const float*)d_in[0];   // (8,128,56,56)
    const float* ow = (const float*)d_in[1];   // (18,128,3,3)
    const float* ob = (const float*)d_in[2];   // (18,)
    const float* cw = (const float*)d_in[3];   // (128,128,3,3)
    float* out  = (float*)d_out;               // (8,128,56,56)
    float* pbuf = (float*)d_ws;                // p values: (8,18,56,56) = 1.8 MB

    dim3 g1((HW + 255) / 256, Bn * 18);        // 13 x 144
    offset_p_kernel<<<g1, 256, 0, stream>>>(x, ow, ob, pbuf);

    deform_gemm_kernel<<<NPOS / PT, 256, 0, stream>>>(x, cw, pbuf, out);
}

// Round 2
// 271.389 us; speedup vs baseline: 1.5044x; 1.5044x over previous
//
#include <hip/hip_runtime.h>
#include <cstdint>
#include <cstddef>

namespace {

constexpr int Bn   = 8;
constexpr int Cc   = 128;
constexpr int Hh   = 56;
constexpr int Ww   = 56;
constexpr int OUTC = 128;
constexpr int NTAP = 9;
constexpr int HW   = Hh * Ww;      // 3136
constexpr int NPOS = Bn * HW;      // 25088
constexpr int KDIM = Cc * NTAP;    // 1152

constexpr int PT   = 32;           // positions per block
constexpr int CCH  = 64;           // channels per K-chunk
constexpr int KC   = CCH * NTAP;   // 576 k per chunk
constexpr int LROW = KC + 4;       // 580 ushort = 1160B row: 8B-aligned, dword-stride 290 (2-way bank, free)

typedef __attribute__((ext_vector_type(8))) short  short8v;
typedef __attribute__((ext_vector_type(4))) short  short4v;
typedef __attribute__((ext_vector_type(4))) float  float4v;

__device__ __forceinline__ unsigned short f2bf(float f) {
    union { float f; uint32_t u; } v; v.f = f;
    const uint32_t u = v.u;
    return (unsigned short)((u + 0x7fffu + ((u >> 16) & 1u)) >> 16);  // RNE
}

// ---------------------------------------------------------------------------
// K0: convert conv weights fp32 -> bf16 (layout preserved: [o][c*9+tap])
// ---------------------------------------------------------------------------
__global__ __launch_bounds__(256) void wconv_kernel(
        const float* __restrict__ cw, unsigned short* __restrict__ cwb) {
    const int i = blockIdx.x * 256 + threadIdx.x;
    if (i < OUTC * KDIM) cwb[i] = f2bf(cw[i]);
}

// ---------------------------------------------------------------------------
// K1: offset conv + p. Thread = (pos, 16-ch slice), ALL 18 m per thread
// (x read once per (pos,slice) -> 18x less cache traffic than R1).
// Deterministic 8-way LDS reduce.
// ---------------------------------------------------------------------------
__global__ __launch_bounds__(256) void offset_p_kernel(
        const float* __restrict__ x, const float* __restrict__ ow,
        const float* __restrict__ ob, float* __restrict__ pbuf) {
    __shared__ float red[8 * PT * 18];           // [g][lp][m] = g*576 + lp*18 + m

    const int t  = threadIdx.x;
    const int lp = t & 31, g = t >> 5;
    const int p0g = blockIdx.x * PT;
    const int b   = p0g / HW;
    const int ijb = p0g % HW;
    const int ij  = ijb + lp;
    const int i   = ij / Ww, j = ij % Ww;
    const float* xb = x + (size_t)b * Cc * HW;

    float acc[18];
#pragma unroll
    for (int m = 0; m < 18; ++m) acc[m] = 0.f;

    for (int cc = 0; cc < 16; ++cc) {
        const int c = g * 16 + cc;
        const float* xc = xb + (size_t)c * HW;
        float xv[9];
#pragma unroll
        for (int ky = 0; ky < 3; ++ky) {
            const int y = i + ky - 1;
            const bool yv = (unsigned)y < (unsigned)Hh;
#pragma unroll
            for (int kx = 0; kx < 3; ++kx) {
                const int xx = j + kx - 1;
                xv[ky * 3 + kx] = (yv && (unsigned)xx < (unsigned)Ww) ? xc[y * Ww + xx] : 0.f;
            }
        }
        const float* wc = ow + c * NTAP;         // w[m][c][tap] = ow[m*1152 + c*9 + tap]
#pragma unroll
        for (int m = 0; m < 18; ++m) {
            const float* wp = wc + m * KDIM;
#pragma unroll
            for (int tap = 0; tap < 9; ++tap)
                acc[m] = fmaf(wp[tap], xv[tap], acc[m]);
        }
    }

#pragma unroll
    for (int m = 0; m < 18; ++m) red[g * 576 + lp * 18 + m] = acc[m];
    __syncthreads();

    for (int e = t; e < 576; e += 256) {         // e = lpe*18 + m
        const int lpe = e / 18, m = e % 18;
        float s = 0.f;
#pragma unroll
        for (int gg = 0; gg < 8; ++gg) s += red[gg * 576 + e];
        s += ob[m];
        const int ije = ijb + lpe;
        const int ie = ije / Ww, je = ije % Ww;
        const float base = (m < 9) ? (float)(ie + m / 3) : (float)(je + (m - 9) % 3);
        pbuf[(size_t)(b * 18 + m) * HW + ije] = base + s;
    }
}

// ---------------------------------------------------------------------------
// K2: fused sampling (fp32-exact, -> bf16 LDS) + MFMA GEMM (16x16x32 bf16).
// Block: 32 pos x 128 out, 4 waves; wave owns 2 out-tiles x 2 pos-tiles.
// ---------------------------------------------------------------------------
__global__ __launch_bounds__(256) void deform_mfma_kernel(
        const float* __restrict__ x, const unsigned short* __restrict__ cwb,
        const float* __restrict__ pbuf, float* __restrict__ out) {
    __shared__ unsigned short xoffB[PT * LROW];  // bf16 xoff[pos][k_local]

    const int t    = threadIdx.x;
    const int lp   = t & 31, g = t >> 5;
    const int lane = t & 63;
    const int mm   = lane & 15, quad = lane >> 4;
    const int wv   = t >> 6;
    const int p0g  = blockIdx.x * PT;
    const int b    = p0g / HW;
    const int ijb  = p0g % HW;
    const int ij   = ijb + lp;
    const float* xb = x + (size_t)b * Cc * HW;

    float4v acc00 = {0.f, 0.f, 0.f, 0.f}, acc01 = {0.f, 0.f, 0.f, 0.f};
    float4v acc10 = {0.f, 0.f, 0.f, 0.f}, acc11 = {0.f, 0.f, 0.f, 0.f};

    for (int c0 = 0; c0 < Cc; c0 += CCH) {
        if (c0) __syncthreads();

        // ---- sampling: thread sweeps 72 (n,ci) cells for its pos lp ----
        int cell = g * 72;
        const int cellEnd = cell + 72;
        while (cell < cellEnd) {
            const int n = cell >> 6, ci0 = cell & 63;
            // exact reference arithmetic (fp32) for bilinear-with-trunc params
            const float py = pbuf[(size_t)(b * 18 + n) * HW + ij];
            const float px = pbuf[(size_t)(b * 18 + 9 + n) * HW + ij];
            const float q0y = floorf(py), q0x = floorf(px);
            const float lty = fminf(fmaxf(q0y, 0.f), 57.f);
            const float ltx = fminf(fmaxf(q0x, 0.f), 57.f);
            const float rby = fminf(fmaxf(q0y + 1.f, 0.f), 57.f);
            const float rbx = fminf(fmaxf(q0x + 1.f, 0.f), 57.f);
            const float pyc = fminf(fmaxf(py, 0.f), 57.f);
            const float pxc = fminf(fmaxf(px, 0.f), 57.f);
            float g0 = (1.f - (pyc - lty)) * truncf(1.f - (pxc - ltx));
            float g1 = (1.f - (rby - pyc)) * truncf(1.f - (rbx - pxc));
            float g2 = (1.f - (pyc - lty)) * (1.f - (rbx - pxc));
            float g3 = (1.f - (rby - pyc)) * (1.f - (pxc - ltx));
            // padded->raw coords; OOB corner == padded zero -> zero its weight
            const int y0 = (int)lty - 1, x0 = (int)ltx - 1;
            const int y1 = (int)rby - 1, x1 = (int)rbx - 1;
            const bool v0y = (unsigned)y0 < (unsigned)Hh, v0x = (unsigned)x0 < (unsigned)Ww;
            const bool v1y = (unsigned)y1 < (unsigned)Hh, v1x = (unsigned)x1 < (unsigned)Ww;
            int o0 = y0 * Ww + x0, o1 = y1 * Ww + x1, o2 = y0 * Ww + x1, o3 = y1 * Ww + x0;
            if (!(v0y && v0x)) { o0 = 0; g0 = 0.f; }
            if (!(v1y && v1x)) { o1 = 0; g1 = 0.f; }
            if (!(v0y && v1x)) { o2 = 0; g2 = 0.f; }
            if (!(v1y && v0x)) { o3 = 0; g3 = 0.f; }

            const int ciEnd = (64 < ci0 + (cellEnd - cell)) ? 64 : ci0 + (cellEnd - cell);
            const float* xc = xb + (size_t)(c0 + ci0) * HW;
            unsigned short* dst = &xoffB[lp * LROW + ci0 * NTAP + n];
            for (int ci = ci0; ci < ciEnd; ++ci) {
                float v = g0 * xc[o0];
                v = fmaf(g1, xc[o1], v);
                v = fmaf(g2, xc[o2], v);
                v = fmaf(g3, xc[o3], v);
                *dst = f2bf(v);
                xc += HW; dst += NTAP;
            }
            cell += ciEnd - ci0;
        }
        __syncthreads();

        // ---- MFMA GEMM over this K-chunk ----
        // B frags straight from L2: lane holds cwb[o = base+mm][k..k+8)
        const unsigned short* bw0 = cwb + (size_t)(wv * 32 + mm) * KDIM + c0 * NTAP;
        const unsigned short* bw1 = bw0 + 16 * KDIM;
        const unsigned short* a0p = &xoffB[mm * LROW + quad * 8];
        const unsigned short* a1p = a0p + 16 * LROW;
#pragma unroll 3
        for (int ks = 0; ks < KC / 32; ++ks) {
            const int kl = ks * 32;
            const short4v a0lo = *(const short4v*)(a0p + kl);
            const short4v a0hi = *(const short4v*)(a0p + kl + 4);
            const short4v a1lo = *(const short4v*)(a1p + kl);
            const short4v a1hi = *(const short4v*)(a1p + kl + 4);
            const short8v a0 = __builtin_shufflevector(a0lo, a0hi, 0, 1, 2, 3, 4, 5, 6, 7);
            const short8v a1 = __builtin_shufflevector(a1lo, a1hi, 0, 1, 2, 3, 4, 5, 6, 7);
            const short8v b0 = *(const short8v*)(bw0 + kl + quad * 8);
            const short8v b1 = *(const short8v*)(bw1 + kl + quad * 8);
            acc00 = __builtin_amdgcn_mfma_f32_16x16x32_bf16(a0, b0, acc00, 0, 0, 0);
            acc01 = __builtin_amdgcn_mfma_f32_16x16x32_bf16(a0, b1, acc01, 0, 0, 0);
            acc10 = __builtin_amdgcn_mfma_f32_16x16x32_bf16(a1, b0, acc10, 0, 0, 0);
            acc11 = __builtin_amdgcn_mfma_f32_16x16x32_bf16(a1, b1, acc11, 0, 0, 0);
        }
    }

    // ---- epilogue: D row = pos = pt*16+quad*4+r (contiguous -> float4 store) ----
    const int obase = wv * 32 + mm;
    float* op00 = out + (size_t)(b * OUTC + obase) * HW + ijb + quad * 4;
    *(float4v*)op00 = acc00;                       // pt=0, ot=0
    *(float4v*)(op00 + 16) = acc10;                // pt=1, ot=0
    float* op01 = op00 + (size_t)16 * HW;
    *(float4v*)op01 = acc01;                       // pt=0, ot=1
    *(float4v*)(op01 + 16) = acc11;                // pt=1, ot=1
}

}  // namespace

extern "C" void kernel_launch(void* const* d_in, const int* in_sizes, int n_in,
                              void* d_out, int out_size, void* d_ws, size_t ws_size,
                              hipStream_t stream) {
    const float* x  = (const float*)d_in[0];   // (8,128,56,56)
    const float* ow = (const float*)d_in[1];   // (18,128,3,3)
    const float* ob = (const float*)d_in[2];   // (18,)
    const float* cw = (const float*)d_in[3];   // (128,128,3,3)
    float* out = (float*)d_out;                // (8,128,56,56)

    float* pbuf = (float*)d_ws;                                    // 8*18*3136 fp32 = 1.81 MB
    unsigned short* cwb = (unsigned short*)((char*)d_ws + (size_t)Bn * 18 * HW * 4);  // 288 KB

    wconv_kernel<<<(OUTC * KDIM + 255) / 256, 256, 0, stream>>>(cw, cwb);
    offset_p_kernel<<<NPOS / PT, 256, 0, stream>>>(x, ow, ob, pbuf);
    deform_mfma_kernel<<<NPOS / PT, 256, 0, stream>>>(x, cwb, pbuf, out);
}

// Round 4
// 207.578 us; speedup vs baseline: 1.9669x; 1.3074x over previous
//
#include <hip/hip_runtime.h>
#include <cstdint>
#include <cstddef>

namespace {

constexpr int Bn   = 8;
constexpr int Cc   = 128;
constexpr int Hh   = 56;
constexpr int Ww   = 56;
constexpr int OUTC = 128;
constexpr int NTAP = 9;
constexpr int HW   = 3136;
constexpr int NPOS = Bn * HW;      // 25088
constexpr int KDIM = 1152;         // Cc*NTAP

constexpr int PT   = 32;           // K2 positions per block
constexpr int CCH  = 32;           // K2 channels per chunk
constexpr int KC   = CCH * NTAP;   // 288
constexpr int LROW = 292;          // ushort row stride (584 B, 8B-aligned)

typedef __attribute__((ext_vector_type(8))) short  short8v;
typedef __attribute__((ext_vector_type(4))) short  short4v;
typedef __attribute__((ext_vector_type(4))) float  float4v;

__device__ __forceinline__ unsigned short f2bf(float f) {
    union { float f; uint32_t u; } v; v.f = f;
    const uint32_t u = v.u;
    return (unsigned short)((u + 0x7fffu + ((u >> 16) & 1u)) >> 16);  // RNE
}

// ---------------------------------------------------------------------------
// K0: permute conv weights to bf16, k' = cc*288 + n*32 + ci  (cc=c/32, ci=c%32)
// ---------------------------------------------------------------------------
__global__ __launch_bounds__(256) void prep_kernel(
        const float* __restrict__ cw, unsigned short* __restrict__ cwb) {
    const int i = blockIdx.x * 256 + threadIdx.x;
    if (i >= OUTC * KDIM) return;
    const int o = i / KDIM, k = i % KDIM;
    const int cc = k / KC, r = k % KC, n = r >> 5, ci = r & 31;
    cwb[i] = f2bf(cw[o * KDIM + (cc * CCH + ci) * NTAP + n]);
}

// ---------------------------------------------------------------------------
// K1: offset conv + p (fp32, BIT-IDENTICAL arithmetic to the R2-verified
// kernel: per-(pos,m) 8 partials over 16-c slices, taps in ky*3+kx order,
// partials summed g=0..7, then +bias, then base+s).
// 512 threads: wave w = channel-group g (wave-uniform -> scalar weight loads),
// lane = position (64 pos/block, coalesced x loads). XCD-swizzled grid.
// ---------------------------------------------------------------------------
__global__ __launch_bounds__(512) void offset_p_kernel(
        const float* __restrict__ x, const float* __restrict__ ow,
        const float* __restrict__ ob, float* __restrict__ pbuf) {
    __shared__ float red[8][64 * 18];            // 36.9 KB

    const int t    = threadIdx.x;
    const int lane = t & 63;
    const int g    = __builtin_amdgcn_readfirstlane(t >> 6);   // wave-uniform
    const int blk  = blockIdx.x;
    const int b    = blk & 7;
    const int ijb  = (blk >> 3) * 64;
    const int ij   = ijb + lane;
    const int i    = ij / Ww, j = ij % Ww;
    const float* xb = x + (size_t)b * Cc * HW;

    float acc[18];
#pragma unroll
    for (int m = 0; m < 18; ++m) acc[m] = 0.f;

    for (int cc = 0; cc < 16; ++cc) {
        const int c = g * 16 + cc;
        const float* xc = xb + (size_t)c * HW;
        float xv[9];
#pragma unroll
        for (int ky = 0; ky < 3; ++ky) {
            const int y = i + ky - 1;
            const bool yv = (unsigned)y < (unsigned)Hh;
#pragma unroll
            for (int kx = 0; kx < 3; ++kx) {
                const int xx = j + kx - 1;
                xv[ky * 3 + kx] = (yv && (unsigned)xx < (unsigned)Ww) ? xc[y * Ww + xx] : 0.f;
            }
        }
        const float* wc = ow + c * NTAP;         // wave-uniform pointer
#pragma unroll
        for (int m = 0; m < 18; ++m) {
            const float* wp = wc + m * KDIM;
#pragma unroll
            for (int tap = 0; tap < 9; ++tap)
                acc[m] = fmaf(wp[tap], xv[tap], acc[m]);
        }
    }

#pragma unroll
    for (int m = 0; m < 18; ++m) red[g][lane * 18 + m] = acc[m];
    __syncthreads();

    for (int e = t; e < 64 * 18; e += 512) {
        const int lpe = e / 18, m = e % 18;
        float s = 0.f;
#pragma unroll
        for (int gg = 0; gg < 8; ++gg) s += red[gg][e];
        s += ob[m];
        const int ije = ijb + lpe;
        const float base = (m < 9) ? (float)(ije / Ww + m / 3)
                                   : (float)(ije % Ww + (m - 9) % 3);
        pbuf[(size_t)(b * 18 + m) * HW + ije] = base + s;
    }
}

// ---------------------------------------------------------------------------
// K2: fused sampling (fp32-exact params in REGISTERS) + MFMA GEMM.
// Block: 32 pos x 128 out, 256 threads. Wave = out-tile pair AND 8-ch
// staging slice... staging: thread (lp=t&31, sl=t>>5) covers 4 channels.
// Grid XCD-swizzled: b = blk&7 -> x[b] (1.6MB) resident in one XCD's L2.
// ---------------------------------------------------------------------------
__global__ __launch_bounds__(256, 3) void deform_mfma_kernel(
        const float* __restrict__ x, const unsigned short* __restrict__ cwb,
        const float* __restrict__ pbuf, float* __restrict__ out) {
    __shared__ unsigned short xoffB[PT * LROW];   // 18.7 KB

    const int t    = threadIdx.x;
    const int lane = t & 63;
    const int mm   = lane & 15, quad = lane >> 4;
    const int wv   = t >> 6;
    const int lp   = t & 31, sl = t >> 5;         // staging: pos, 4-ch slice
    const int blk  = blockIdx.x;
    const int b    = blk & 7;
    const int ijb  = (blk >> 3) * PT;
    const int ij   = ijb + lp;
    const float* xb = x + (size_t)b * Cc * HW;

    // ---- per-thread sampling params for pos lp, all 9 taps (exact fp32) ----
    float g0r[9], g1r[9], g2r[9], g3r[9];
    int o23[9], o01[9];
#pragma unroll
    for (int n = 0; n < 9; ++n) {
        const float py = pbuf[(size_t)(b * 18 + n) * HW + ij];
        const float px = pbuf[(size_t)(b * 18 + 9 + n) * HW + ij];
        const float q0y = floorf(py), q0x = floorf(px);
        const float lty = fminf(fmaxf(q0y, 0.f), 57.f);
        const float ltx = fminf(fmaxf(q0x, 0.f), 57.f);
        const float rby = fminf(fmaxf(q0y + 1.f, 0.f), 57.f);
        const float rbx = fminf(fmaxf(q0x + 1.f, 0.f), 57.f);
        const float pyc = fminf(fmaxf(py, 0.f), 57.f);
        const float pxc = fminf(fmaxf(px, 0.f), 57.f);
        float g0 = (1.f - (pyc - lty)) * truncf(1.f - (pxc - ltx));   // lt
        float g1 = (1.f - (rby - pyc)) * truncf(1.f - (rbx - pxc));   // rb
        float g2 = (1.f - (pyc - lty)) * (1.f - (rbx - pxc));         // lb (lty,rbx)
        float g3 = (1.f - (rby - pyc)) * (1.f - (pxc - ltx));         // rt (rby,ltx)
        const int y0 = (int)lty - 1, x0 = (int)ltx - 1;
        const int y1 = (int)rby - 1, x1 = (int)rbx - 1;
        const bool v0y = (unsigned)y0 < (unsigned)Hh, v0x = (unsigned)x0 < (unsigned)Ww;
        const bool v1y = (unsigned)y1 < (unsigned)Hh, v1x = (unsigned)x1 < (unsigned)Ww;
        int o0 = y0 * Ww + x0, o1 = y1 * Ww + x1, o2 = y0 * Ww + x1, o3 = y1 * Ww + x0;
        if (!(v0y && v0x)) { o0 = 0; g0 = 0.f; }
        if (!(v1y && v1x)) { o1 = 0; g1 = 0.f; }
        if (!(v0y && v1x)) { o2 = 0; g2 = 0.f; }
        if (!(v1y && v0x)) { o3 = 0; g3 = 0.f; }
        g0r[n] = g0; g1r[n] = g1; g2r[n] = g2; g3r[n] = g3;
        o23[n] = (o2 & 0xffff) | (o3 << 16);
        o01[n] = (o0 & 0xffff) | (o1 << 16);
    }

    float4v acc[2][2] = { { {0.f,0.f,0.f,0.f}, {0.f,0.f,0.f,0.f} },
                          { {0.f,0.f,0.f,0.f}, {0.f,0.f,0.f,0.f} } };

    for (int cc = 0; cc < 4; ++cc) {
        if (cc) __syncthreads();

        // ---- sampling stage: 4 channels per thread, 2-gather fast path ----
        const float* xc0 = xb + (size_t)(cc * CCH + sl * 4) * HW;
#pragma unroll
        for (int n = 0; n < 9; ++n) {
            const int o2 = o23[n] & 0xffff, o3 = (o23[n] >> 16) & 0xffff;
            const float g2 = g2r[n], g3 = g3r[n];
            const bool slow = (g0r[n] != 0.f) | (g1r[n] != 0.f);
            float v[4];
            if (__ballot(slow) == 0) {
                float a2[4], a3[4];
#pragma unroll
                for (int u = 0; u < 4; ++u) a2[u] = xc0[(size_t)u * HW + o2];
#pragma unroll
                for (int u = 0; u < 4; ++u) a3[u] = xc0[(size_t)u * HW + o3];
#pragma unroll
                for (int u = 0; u < 4; ++u) v[u] = fmaf(g2, a2[u], g3 * a3[u]);
            } else {
                const int o0 = o01[n] & 0xffff, o1 = (o01[n] >> 16) & 0xffff;
                const float g0 = g0r[n], g1 = g1r[n];
                float a2[4], a3[4], a0[4], a1[4];
#pragma unroll
                for (int u = 0; u < 4; ++u) a2[u] = xc0[(size_t)u * HW + o2];
#pragma unroll
                for (int u = 0; u < 4; ++u) a3[u] = xc0[(size_t)u * HW + o3];
#pragma unroll
                for (int u = 0; u < 4; ++u) a0[u] = xc0[(size_t)u * HW + o0];
#pragma unroll
                for (int u = 0; u < 4; ++u) a1[u] = xc0[(size_t)u * HW + o1];
#pragma unroll
                for (int u = 0; u < 4; ++u)
                    v[u] = fmaf(g2, a2[u], fmaf(g3, a3[u], fmaf(g0, a0[u], g1 * a1[u])));
            }
            short4v pk = { (short)f2bf(v[0]), (short)f2bf(v[1]),
                           (short)f2bf(v[2]), (short)f2bf(v[3]) };
            *(short4v*)&xoffB[lp * LROW + n * CCH + sl * 4] = pk;   // 8B-aligned
        }
        __syncthreads();

        // ---- MFMA GEMM over this chunk: 2 pos-tiles x 2 out-tiles ----
        const unsigned short* bw0 = cwb + (size_t)(wv * 32 + mm) * KDIM + cc * KC;
        const unsigned short* bw1 = bw0 + 16 * KDIM;
        const unsigned short* ap0 = &xoffB[mm * LROW + quad * 8];
#pragma unroll 3
        for (int ks = 0; ks < KC / 32; ++ks) {    // 9 steps
            const int kl = ks * 32;
            const short8v b0 = *(const short8v*)(bw0 + kl + quad * 8);
            const short8v b1 = *(const short8v*)(bw1 + kl + quad * 8);
#pragma unroll
            for (int pt = 0; pt < 2; ++pt) {
                const unsigned short* ap = ap0 + pt * 16 * LROW + kl;
                const short4v alo = *(const short4v*)ap;
                const short4v ahi = *(const short4v*)(ap + 4);
                const short8v a = __builtin_shufflevector(alo, ahi, 0, 1, 2, 3, 4, 5, 6, 7);
                acc[pt][0] = __builtin_amdgcn_mfma_f32_16x16x32_bf16(a, b0, acc[pt][0], 0, 0, 0);
                acc[pt][1] = __builtin_amdgcn_mfma_f32_16x16x32_bf16(a, b1, acc[pt][1], 0, 0, 0);
            }
        }
    }

    // ---- epilogue (D: row=pos=pt*16+quad*4+r, col=out=base+mm; verified R2) ----
    float* ob0 = out + (size_t)(b * OUTC + wv * 32 + mm) * HW + ijb + quad * 4;
#pragma unroll
    for (int pt = 0; pt < 2; ++pt) {
        *(float4v*)(ob0 + pt * 16) = acc[pt][0];
        *(float4v*)(ob0 + (size_t)16 * HW + pt * 16) = acc[pt][1];
    }
}

}  // namespace

extern "C" void kernel_launch(void* const* d_in, const int* in_sizes, int n_in,
                              void* d_out, int out_size, void* d_ws, size_t ws_size,
                              hipStream_t stream) {
    const float* x  = (const float*)d_in[0];   // (8,128,56,56)
    const float* ow = (const float*)d_in[1];   // (18,128,3,3)
    const float* ob = (const float*)d_in[2];   // (18,)
    const float* cw = (const float*)d_in[3];   // (128,128,3,3)
    float* out = (float*)d_out;                // (8,128,56,56)

    float* pbuf = (float*)d_ws;                                        // 2.26 MB
    unsigned short* cwb = (unsigned short*)((char*)d_ws + (size_t)Bn * 18 * HW * 4);

    prep_kernel<<<(OUTC * KDIM + 255) / 256, 256, 0, stream>>>(cw, cwb);
    offset_p_kernel<<<NPOS / 64, 512, 0, stream>>>(x, ow, ob, pbuf);
    deform_mfma_kernel<<<NPOS / PT, 256, 0, stream>>>(x, cwb, pbuf, out);
}

// Round 5
// 173.721 us; speedup vs baseline: 2.3502x; 1.1949x over previous
//
#include <hip/hip_runtime.h>
#include <cstdint>
#include <cstddef>

namespace {

constexpr int Bn   = 8;
constexpr int Cc   = 128;
constexpr int Hh   = 56;
constexpr int Ww   = 56;
constexpr int OUTC = 128;
constexpr int NTAP = 9;
constexpr int HW   = 3136;
constexpr int NPOS = Bn * HW;      // 25088
constexpr int KDIM = 1152;         // Cc*NTAP

constexpr int PT   = 32;           // K2 positions per block
constexpr int CCH  = 64;           // K2 channels per chunk (2 chunks)
constexpr int KC   = CCH * NTAP;   // 576
constexpr int LROW = 584;          // ushort row stride (1168B, 16B-aligned)

typedef __attribute__((ext_vector_type(8))) short  short8v;
typedef __attribute__((ext_vector_type(4))) short  short4v;
typedef __attribute__((ext_vector_type(4))) float  float4v;

__device__ __forceinline__ unsigned short f2bf(float f) {
    union { float f; uint32_t u; } v; v.f = f;
    const uint32_t u = v.u;
    return (unsigned short)((u + 0x7fffu + ((u >> 16) & 1u)) >> 16);  // RNE
}
__device__ __forceinline__ float bf2f(unsigned short us) {
    union { uint32_t u; float f; } v; v.u = (uint32_t)us << 16;
    return v.f;
}

// ---------------------------------------------------------------------------
// Prep: (a) permute conv weights to bf16 with k' = cc*576 + n*64 + cl
//       (b) transpose x -> xt[b][ij][c] bf16 (channel-last)
// ---------------------------------------------------------------------------
__global__ __launch_bounds__(256) void prep_kernel(
        const float* __restrict__ cw, const float* __restrict__ x,
        unsigned short* __restrict__ cwb, unsigned short* __restrict__ xt) {
    const int blk = blockIdx.x;
    if (blk < 576) {                               // weights: 128*1152 elems
        const int i = blk * 256 + threadIdx.x;
        const int o = i / KDIM, k = i % KDIM;
        const int cc = k / KC, r = k % KC, n = r >> 6, cl = r & 63;
        cwb[i] = f2bf(cw[o * KDIM + (cc * CCH + cl) * NTAP + n]);
        return;
    }
    const int blk2 = blk - 576;                    // transpose: 392 blocks
    const int b = blk2 & 7;
    const int ijb = (blk2 >> 3) * 64;
    const int lp = threadIdx.x & 63, cg = threadIdx.x >> 6;
    const float* xb = x + (size_t)b * Cc * HW + ijb + lp;
    unsigned short* xr = xt + ((size_t)b * HW + ijb + lp) * Cc + cg * 32;
#pragma unroll
    for (int c8 = 0; c8 < 4; ++c8) {
        short8v sv;
#pragma unroll
        for (int u = 0; u < 8; ++u)
            sv[u] = (short)f2bf(xb[(size_t)(cg * 32 + c8 * 8 + u) * HW]);
        *(short8v*)(xr + c8 * 8) = sv;
    }
}

// ---------------------------------------------------------------------------
// K1: offset conv + p. 8x8 spatial tile per block, 512 thr = 64 pos x 8
// c-slices. x halo (128ch x 10x10) staged ONCE in LDS; weights scalar-loaded
// (wave-uniform); red[] reuses the LDS after a barrier.
// FP order BIT-IDENTICAL to R4's pbuf (proven corner decisions).
// ---------------------------------------------------------------------------
__global__ __launch_bounds__(512, 6) void offset_p_kernel(
        const float* __restrict__ x, const float* __restrict__ ow,
        const float* __restrict__ ob, float* __restrict__ pbuf) {
    __shared__ float smem[Cc * 100];               // 51.2 KB; red overlays later

    const int t    = threadIdx.x;
    const int lane = t & 63;                       // position in 8x8 tile
    const int g    = __builtin_amdgcn_readfirstlane(t >> 6);
    const int blk  = blockIdx.x;
    const int b    = blk & 7;                      // XCD affinity
    const int tile = blk >> 3;                     // 0..48
    const int ti = tile / 7, tj = tile % 7;
    const int dy = lane >> 3, dx = lane & 7;
    const float* xb = x + (size_t)b * Cc * HW;

    // ---- stage halo: rows ti*8-1 .. ti*8+8, cols tj*8-1 .. tj*8+8 ----
    const int gy0 = ti * 8 - 1, gx0 = tj * 8 - 1;
    for (int e = t; e < Cc * 100; e += 512) {
        const int c = e / 100, r = e % 100, y = r / 10, xx = r % 10;
        const int gy = gy0 + y, gx = gx0 + xx;
        const bool v = ((unsigned)gy < (unsigned)Hh) & ((unsigned)gx < (unsigned)Ww);
        smem[e] = v ? xb[(size_t)c * HW + gy * Ww + gx] : 0.f;
    }
    __syncthreads();

    // ---- per-slice partials (order == R4) ----
    float acc[18];
#pragma unroll
    for (int m = 0; m < 18; ++m) acc[m] = 0.f;

    for (int cc = 0; cc < 16; ++cc) {
        const int c = g * 16 + cc;
        const float* xs = &smem[c * 100 + dy * 10 + dx];
        float xv[9];
#pragma unroll
        for (int ky = 0; ky < 3; ++ky)
#pragma unroll
            for (int kx = 0; kx < 3; ++kx)
                xv[ky * 3 + kx] = xs[ky * 10 + kx];
        const float* wc = ow + c * NTAP;           // wave-uniform
#pragma unroll
        for (int m = 0; m < 18; ++m) {
            const float* wp = wc + m * KDIM;
#pragma unroll
            for (int tap = 0; tap < 9; ++tap)
                acc[m] = fmaf(wp[tap], xv[tap], acc[m]);
        }
    }
    __syncthreads();                               // all xs reads done

    float* red = smem;                             // [g][pos*18+m], 9216 floats
#pragma unroll
    for (int m = 0; m < 18; ++m) red[g * 1152 + lane * 18 + m] = acc[m];
    __syncthreads();

    for (int e = t; e < 64 * 18; e += 512) {
        const int lpe = e / 18, m = e % 18;
        float s = 0.f;
#pragma unroll
        for (int gg = 0; gg < 8; ++gg) s += red[gg * 1152 + e];
        s += ob[m];
        const int ije = (ti * 8 + (lpe >> 3)) * Ww + tj * 8 + (lpe & 7);
        const float base = (m < 9) ? (float)(ije / Ww + m / 3)
                                   : (float)(ije % Ww + (m - 9) % 3);
        pbuf[(size_t)(b * 18 + m) * HW + ije] = base + s;
    }
}

// ---------------------------------------------------------------------------
// K2: branchless 4-corner sampling from channel-last bf16 xt + MFMA GEMM.
// Params (exact fp32 trunc-bilinear) computed once per (pos,tap) into LDS.
// Staging thread = (pos, 8ch-group): 4 x dwordx4 gathers, zero branches.
// ---------------------------------------------------------------------------
__global__ __launch_bounds__(256, 3) void deform_mfma_kernel(
        const unsigned short* __restrict__ xt, const unsigned short* __restrict__ cwb,
        const float* __restrict__ pbuf, float* __restrict__ out) {
    __shared__ unsigned short xoffB[PT * LROW];    // 36.5 KB
    __shared__ float4v pgS[PT * NTAP];             // {g2,g3,g0,g1}  4.6 KB
    __shared__ int2    poS[PT * NTAP];             // {o2|o3<<16, o0|o1<<16}

    const int t    = threadIdx.x;
    const int lane = t & 63;
    const int mm   = lane & 15, quad = lane >> 4;
    const int wv   = t >> 6;
    const int lp   = t & 31, grp = t >> 5;         // staging: pos, 8-ch group
    const int blk  = blockIdx.x;
    const int b    = blk & 7;                      // XCD affinity
    const int ijb  = (blk >> 3) * PT;
    const unsigned short* xtb = xt + (size_t)b * HW * Cc;

    // ---- params: exact fp32, once per (pos,tap); e = n*32 + pos ----
    for (int e = t; e < PT * NTAP; e += 256) {
        const int n = e >> 5, lpe = e & 31;
        const int ij = ijb + lpe;
        const float py = pbuf[(size_t)(b * 18 + n) * HW + ij];
        const float px = pbuf[(size_t)(b * 18 + 9 + n) * HW + ij];
        const float q0y = floorf(py), q0x = floorf(px);
        const float lty = fminf(fmaxf(q0y, 0.f), 57.f);
        const float ltx = fminf(fmaxf(q0x, 0.f), 57.f);
        const float rby = fminf(fmaxf(q0y + 1.f, 0.f), 57.f);
        const float rbx = fminf(fmaxf(q0x + 1.f, 0.f), 57.f);
        const float pyc = fminf(fmaxf(py, 0.f), 57.f);
        const float pxc = fminf(fmaxf(px, 0.f), 57.f);
        float g0 = (1.f - (pyc - lty)) * truncf(1.f - (pxc - ltx));   // lt
        float g1 = (1.f - (rby - pyc)) * truncf(1.f - (rbx - pxc));   // rb
        float g2 = (1.f - (pyc - lty)) * (1.f - (rbx - pxc));         // lb (lty,rbx)
        float g3 = (1.f - (rby - pyc)) * (1.f - (pxc - ltx));         // rt (rby,ltx)
        const int y0 = (int)lty - 1, x0 = (int)ltx - 1;
        const int y1 = (int)rby - 1, x1 = (int)rbx - 1;
        const bool v0y = (unsigned)y0 < (unsigned)Hh, v0x = (unsigned)x0 < (unsigned)Ww;
        const bool v1y = (unsigned)y1 < (unsigned)Hh, v1x = (unsigned)x1 < (unsigned)Ww;
        int o0 = y0 * Ww + x0, o1 = y1 * Ww + x1, o2 = y0 * Ww + x1, o3 = y1 * Ww + x0;
        if (!(v0y && v0x)) { o0 = 0; g0 = 0.f; }
        if (!(v1y && v1x)) { o1 = 0; g1 = 0.f; }
        if (!(v0y && v1x)) { o2 = 0; g2 = 0.f; }
        if (!(v1y && v0x)) { o3 = 0; g3 = 0.f; }
        pgS[e] = (float4v){ g2, g3, g0, g1 };
        poS[e] = make_int2((o2 & 0xffff) | (o3 << 16), (o0 & 0xffff) | (o1 << 16));
    }

    float4v acc[2][2] = { { {0.f,0.f,0.f,0.f}, {0.f,0.f,0.f,0.f} },
                          { {0.f,0.f,0.f,0.f}, {0.f,0.f,0.f,0.f} } };
    __syncthreads();

    for (int cc = 0; cc < 2; ++cc) {
        if (cc) __syncthreads();
        // ---- branchless staging: 9 taps x (4 gathers of 8ch) ----
        const int cbase = cc * CCH + grp * 8;
#pragma unroll
        for (int n = 0; n < 9; ++n) {
            const float4v G = pgS[n * 32 + lp];
            const int2  O = poS[n * 32 + lp];
            const short8v a2 = *(const short8v*)(xtb + (size_t)(O.x & 0xffff) * Cc + cbase);
            const short8v a3 = *(const short8v*)(xtb + (size_t)((O.x >> 16) & 0xffff) * Cc + cbase);
            const short8v a0 = *(const short8v*)(xtb + (size_t)(O.y & 0xffff) * Cc + cbase);
            const short8v a1 = *(const short8v*)(xtb + (size_t)((O.y >> 16) & 0xffff) * Cc + cbase);
            short8v sv;
#pragma unroll
            for (int u = 0; u < 8; ++u) {
                float v = G.x * bf2f((unsigned short)a2[u]);
                v = fmaf(G.y, bf2f((unsigned short)a3[u]), v);
                v = fmaf(G.z, bf2f((unsigned short)a0[u]), v);
                v = fmaf(G.w, bf2f((unsigned short)a1[u]), v);
                sv[u] = (short)f2bf(v);
            }
            *(short8v*)&xoffB[lp * LROW + n * CCH + grp * 8] = sv;
        }
        __syncthreads();

        // ---- MFMA GEMM: 18 ks-steps, B straight from L2 ----
        const unsigned short* bw0 = cwb + (size_t)(wv * 32 + mm) * KDIM + cc * KC;
        const unsigned short* bw1 = bw0 + 16 * KDIM;
        const unsigned short* ap0 = &xoffB[mm * LROW + quad * 8];
#pragma unroll 3
        for (int ks = 0; ks < KC / 32; ++ks) {
            const int kl = ks * 32;
            const short8v b0 = *(const short8v*)(bw0 + kl + quad * 8);
            const short8v b1 = *(const short8v*)(bw1 + kl + quad * 8);
#pragma unroll
            for (int pt = 0; pt < 2; ++pt) {
                const unsigned short* ap = ap0 + pt * 16 * LROW + kl;
                const short4v alo = *(const short4v*)ap;
                const short4v ahi = *(const short4v*)(ap + 4);
                const short8v a = __builtin_shufflevector(alo, ahi, 0, 1, 2, 3, 4, 5, 6, 7);
                acc[pt][0] = __builtin_amdgcn_mfma_f32_16x16x32_bf16(a, b0, acc[pt][0], 0, 0, 0);
                acc[pt][1] = __builtin_amdgcn_mfma_f32_16x16x32_bf16(a, b1, acc[pt][1], 0, 0, 0);
            }
        }
    }

    // ---- epilogue (layout verified R2/R4) ----
    float* ob0 = out + (size_t)(b * OUTC + wv * 32 + mm) * HW + ijb + quad * 4;
#pragma unroll
    for (int pt = 0; pt < 2; ++pt) {
        *(float4v*)(ob0 + pt * 16) = acc[pt][0];
        *(float4v*)(ob0 + (size_t)16 * HW + pt * 16) = acc[pt][1];
    }
}

}  // namespace

extern "C" void kernel_launch(void* const* d_in, const int* in_sizes, int n_in,
                              void* d_out, int out_size, void* d_ws, size_t ws_size,
                              hipStream_t stream) {
    const float* x  = (const float*)d_in[0];   // (8,128,56,56)
    const float* ow = (const float*)d_in[1];   // (18,128,3,3)
    const float* ob = (const float*)d_in[2];   // (18,)
    const float* cw = (const float*)d_in[3];   // (128,128,3,3)
    float* out = (float*)d_out;                // (8,128,56,56)

    char* wsp = (char*)d_ws;
    float* pbuf = (float*)wsp;                                   // 1.81 MB
    unsigned short* cwb = (unsigned short*)(wsp + 1806336);      // 288 KB
    unsigned short* xt  = (unsigned short*)(wsp + 1806336 + 294912);  // 6.42 MB

    prep_kernel<<<576 + 392, 256, 0, stream>>>(cw, x, cwb, xt);
    offset_p_kernel<<<NPOS / 64, 512, 0, stream>>>(x, ow, ob, pbuf);
    deform_mfma_kernel<<<NPOS / PT, 256, 0, stream>>>(xt, cwb, pbuf, out);
}